// Round 9
// baseline (196.540 us; speedup 1.0000x reference)
//
#include <hip/hip_runtime.h>
#include <hip/hip_bf16.h>

#define H_  12
#define S_  2048
#define D_  768
#define DK_ 64

typedef __bf16 bf16x8 __attribute__((ext_vector_type(8)));
typedef __bf16 bf16x4 __attribute__((ext_vector_type(4)));
typedef short  short4v __attribute__((ext_vector_type(4)));
typedef float  f32x4  __attribute__((ext_vector_type(4)));

// 0.125 * log2(e): folded attention scale so flash can use exp2 directly
#define QSCALE 0.1803368801111137f

__device__ inline float exp2_fast(float x) {
  return __builtin_amdgcn_exp2f(x);
}

__device__ inline f32x4 mfma_bf16(bf16x8 a, bf16x8 b, f32x4 c) {
  return __builtin_amdgcn_mfma_f32_16x16x32_bf16(a, b, c, 0, 0, 0);
}

__device__ inline f32x4 mfma16(bf16x4 a, bf16x4 b, f32x4 c) {
#if __has_builtin(__builtin_amdgcn_mfma_f32_16x16x16bf16_1k)
  short4v as = __builtin_bit_cast(short4v, a);
  short4v bs = __builtin_bit_cast(short4v, b);
  return __builtin_amdgcn_mfma_f32_16x16x16bf16_1k(as, bs, c, 0, 0, 0);
#else
  asm("s_nop 1\n\tv_mfma_f32_16x16x16_bf16 %0, %1, %2, %0"
      : "+v"(c) : "v"(a), "v"(b));
  return c;
#endif
}

__device__ inline void gload16(const void* g, void* l) {
  __builtin_amdgcn_global_load_lds(
      (const __attribute__((address_space(1))) void*)g,
      (__attribute__((address_space(3))) void*)l, 16, 0, 0);
}

__device__ inline bf16x8 cvt2bf16(f32x4 a, f32x4 b) {
  bf16x8 r;
  r[0] = (__bf16)a[0]; r[1] = (__bf16)a[1];
  r[2] = (__bf16)a[2]; r[3] = (__bf16)a[3];
  r[4] = (__bf16)b[0]; r[5] = (__bf16)b[1];
  r[6] = (__bf16)b[2]; r[7] = (__bf16)b[3];
  return r;
}

// ---------------------------------------------------------------------------
// Convert the 4 weight matrices (Wq,Wk,Wv,Wo) fp32 -> bf16, concatenated.
// ---------------------------------------------------------------------------
__global__ __launch_bounds__(256)
void conv_w(const float* __restrict__ Wq, const float* __restrict__ Wk,
            const float* __restrict__ Wv, const float* __restrict__ Wo,
            __hip_bfloat16* __restrict__ out)
{
  const int i8 = blockIdx.x * 256 + threadIdx.x;
  const int mat = i8 / 73728;
  const int off = (i8 - mat * 73728) * 8;
  const float* src = (mat == 0) ? Wq : (mat == 1) ? Wk : (mat == 2) ? Wv : Wo;
  f32x4 a = *(const f32x4*)(src + off);
  f32x4 b = *(const f32x4*)(src + off + 4);
  *(bf16x8*)(out + (size_t)mat * 589824 + off) = cvt2bf16(a, b);
}

// ---------------------------------------------------------------------------
// Fused QKV projection v3 (unchanged from r8). Grid (32, 6, 3). 128x128, BK=32.
// z<2: A=X (fp32 reg-roundtrip), B=W (gload16); z==2: roles swapped so V^T
// stores are lane-consecutive.
// ---------------------------------------------------------------------------
__global__ __launch_bounds__(256, 3)
void qkv_proj(const float* __restrict__ Q, const float* __restrict__ K,
              const float* __restrict__ V,
              const __hip_bfloat16* __restrict__ Wb,
              const float* __restrict__ bq, const float* __restrict__ bk,
              const float* __restrict__ bv,
              __hip_bfloat16* __restrict__ q_ws,
              __hip_bfloat16* __restrict__ k_ws,
              __hip_bfloat16* __restrict__ vT_ws)
{
  __shared__ alignas(16) __hip_bfloat16 Ald[128 * 32];
  __shared__ alignas(16) __hip_bfloat16 Bld[128 * 32];

  const int z = blockIdx.z;
  const float* X    = (z == 0) ? Q  : (z == 1) ? K  : V;
  const float* bias = (z == 0) ? bq : (z == 1) ? bk : bv;
  const __hip_bfloat16* Wz = Wb + (size_t)z * 589824;
  __hip_bfloat16* out = (z == 0) ? q_ws : (z == 1) ? k_ws : vT_ws;
  const bool vmode = (z == 2);
  const float osc = (z == 0) ? QSCALE : 1.0f;

  const int t    = threadIdx.x;
  const int w    = t >> 6;
  const int lane = t & 63;
  const int l15  = lane & 15;
  const int quad = lane >> 4;
  const int m0 = blockIdx.x * 128;
  const int n0 = blockIdx.y * 128;
  const int wm = (w >> 1) * 64;
  const int wn = (w & 1) * 64;

  __hip_bfloat16* Xbuf = vmode ? Bld : Ald;
  __hip_bfloat16* Wbuf = vmode ? Ald : Bld;

  const f32x4 fzero = {0.f, 0.f, 0.f, 0.f};
  f32x4 acc[4][4];
#pragma unroll
  for (int i = 0; i < 4; ++i)
#pragma unroll
    for (int j = 0; j < 4; ++j) acc[i][j] = fzero;

  const int ar = t >> 2, ac = t & 3;
  const int sw = ac ^ ((ar >> 1) & 3);
  const float* As0 = X + (size_t)(m0 + ar) * D_ + ac * 8;
  const float* As1 = X + (size_t)(m0 + ar + 64) * D_ + ac * 8;
  __hip_bfloat16* Xw0 = &Xbuf[((ar)      * 4 + sw) * 8];
  __hip_bfloat16* Xw1 = &Xbuf[((ar + 64) * 4 + sw) * 8];

  const int bp = (t & 3) ^ (((t >> 2) >> 1) & 3);
  const __hip_bfloat16* Bs0 = Wz + (size_t)(n0 + (t >> 2)) * D_ + bp * 8;
  const __hip_bfloat16* Bs1 = Wz + (size_t)(n0 + (t >> 2) + 64) * D_ + bp * 8;
  __hip_bfloat16* Wd0 = &Wbuf[t * 8];
  __hip_bfloat16* Wd1 = &Wbuf[(t + 256) * 8];

  int agrn[4], bgrn[4];
#pragma unroll
  for (int i = 0; i < 4; ++i) {
    int row = wm + 16 * i + l15;
    agrn[i] = (row * 4 + (quad ^ ((row >> 1) & 3))) * 8;
    row = wn + 16 * i + l15;
    bgrn[i] = (row * 4 + (quad ^ ((row >> 1) & 3))) * 8;
  }

  f32x4 a00 = *(const f32x4*)As0, a01 = *(const f32x4*)(As0 + 4);
  f32x4 a10 = *(const f32x4*)As1, a11 = *(const f32x4*)(As1 + 4);

  for (int k0 = 0; k0 < D_; k0 += 32) {
    *(bf16x8*)Xw0 = cvt2bf16(a00, a01);
    *(bf16x8*)Xw1 = cvt2bf16(a10, a11);
    gload16(Bs0 + k0, Wd0);
    gload16(Bs1 + k0, Wd1);
    __syncthreads();

    const int kn = k0 + 32;
    if (kn < D_) {
      a00 = *(const f32x4*)(As0 + kn); a01 = *(const f32x4*)(As0 + kn + 4);
      a10 = *(const f32x4*)(As1 + kn); a11 = *(const f32x4*)(As1 + kn + 4);
    }

    bf16x8 af[4], bfr[4];
#pragma unroll
    for (int i = 0; i < 4; ++i) af[i]  = *(const bf16x8*)&Ald[agrn[i]];
#pragma unroll
    for (int j = 0; j < 4; ++j) bfr[j] = *(const bf16x8*)&Bld[bgrn[j]];
#pragma unroll
    for (int i = 0; i < 4; ++i)
#pragma unroll
      for (int j = 0; j < 4; ++j)
        acc[i][j] = mfma_bf16(af[i], bfr[j], acc[i][j]);
    __syncthreads();
  }

  if (!vmode) {
#pragma unroll
    for (int j = 0; j < 4; ++j) {
      const int n_g = n0 + wn + 16 * j + l15;
      const float bv = bias[n_g];
      const int hh = n_g >> 6, dk = n_g & (DK_ - 1);
#pragma unroll
      for (int i = 0; i < 4; ++i) {
        const int mbase = m0 + wm + 16 * i + quad * 4;
#pragma unroll
        for (int r = 0; r < 4; ++r) {
          const int m_g = mbase + r;
          const int bb = m_g >> 11, ss = m_g & (S_ - 1);
          const float vout = (acc[i][j][r] + bv) * osc;
          out[(((size_t)(bb * H_ + hh)) * S_ + ss) * DK_ + dk] =
              __float2bfloat16(vout);
        }
      }
    }
  } else {
#pragma unroll
    for (int i = 0; i < 4; ++i) {
      const int nbase = n0 + wm + 16 * i + quad * 4;
#pragma unroll
      for (int r = 0; r < 4; ++r) {
        const int n_g = nbase + r;
        const float bv = bias[n_g];
        const int hh = n_g >> 6, dk = n_g & (DK_ - 1);
#pragma unroll
        for (int j = 0; j < 4; ++j) {
          const int m_g = m0 + wn + 16 * j + l15;
          const int bb = m_g >> 11, ss = m_g & (S_ - 1);
          out[(((size_t)(bb * H_ + hh)) * DK_ + dk) * S_ + ss] =
              __float2bfloat16(acc[i][j][r] + bv);
        }
      }
    }
  }
}

// ---------------------------------------------------------------------------
// Flash attention v6: split-KV x2. Grid 1536 flat. Block = (pair x, half):
// processes kt = half, half+2, ... so per-block duration halves and 6
// blocks/CU (4 resident via 35.8KB LDS) give real refill. Writes
// UNNORMALIZED accO (bf16) + per-row (m,l) partials; fa_merge combines.
// XCD pin: all blocks of a bh land on one XCD (KV L2-resident, r8-verified).
// ---------------------------------------------------------------------------
__global__ __launch_bounds__(256, 4)
void flash_attn(const __hip_bfloat16* __restrict__ q_ws,
                const __hip_bfloat16* __restrict__ k_ws,
                const __hip_bfloat16* __restrict__ vT_ws,
                __hip_bfloat16* __restrict__ Op0,
                __hip_bfloat16* __restrict__ Op1,
                float2* __restrict__ mlbuf)
{
  __shared__ alignas(16) __hip_bfloat16 Kld[128][72];   // [kr][d]
  __shared__ alignas(16) __hip_bfloat16 Vld[64][136];   // [d][kc]

  const int t = threadIdx.x, w = t >> 6, lane = t & 63;
  const int l15 = lane & 15, quad = lane >> 4;

  // decode: slot = XCD, 6 groups = 3 bh x 2 halves, x permuted per group
  const int id   = blockIdx.x;          // 0..1535
  const int slot = id & 7;
  const int jj   = id >> 3;             // 0..191
  const int grp  = jj >> 5;             // 0..5
  const int bh   = slot + 8 * (grp % 3);
  const int half = grp / 3;             // 0 or 1
  const int x    = ((jj & 31) + 13 * grp) & 31;

  const int tLo = x, tHi = 63 - x;
  const int myTile = (w < 2) ? tLo : tHi;
  const int qbase = myTile * 32 + 16 * (w & 1);
  const int qg = qbase + l15;
  const int myNkt = (myTile >> 2) + 1;
  const int nktT  = (tHi >> 2) + 1;
  const size_t hbase = (size_t)bh * S_ * DK_;
  const size_t vtb   = (size_t)bh * DK_ * S_;

  bf16x8 qf[2];
#pragma unroll
  for (int kk = 0; kk < 2; ++kk)
    qf[kk] = *(const bf16x8*)(q_ws + hbase + (size_t)qg * DK_ + kk * 32 + quad * 8);

  const f32x4 fzero = {0.f, 0.f, 0.f, 0.f};
  f32x4 accO[4];
#pragma unroll
  for (int jd = 0; jd < 4; ++jd) accO[jd] = fzero;
  float mI = -1.0e30f, lI = 0.f;

  const int tr = t >> 3, kg = t & 7;
  const int tv = t >> 4, vg = t & 15;
  const __hip_bfloat16* Kbase = k_ws + hbase + (size_t)tr * DK_ + kg * 8;
  const __hip_bfloat16* Vbase = vT_ws + vtb + (size_t)tv * S_ + vg * 8;

  bf16x8 rK[4], rV[4];
  const int k0h = half * 128;
#pragma unroll
  for (int it = 0; it < 4; ++it) {
    rK[it] = *(const bf16x8*)(Kbase + (size_t)(k0h + 32 * it) * DK_);
    rV[it] = *(const bf16x8*)(Vbase + (size_t)(16 * it) * S_ + k0h);
  }

  for (int kt = half; kt < nktT; kt += 2) {
#pragma unroll
    for (int it = 0; it < 4; ++it) {
      *(bf16x8*)&Kld[32 * it + tr][kg * 8] = rK[it];
      *(bf16x8*)&Vld[16 * it + tv][vg * 8] = rV[it];
    }
    __syncthreads();

    if (kt + 2 < nktT) {
      const int k0n = (kt + 2) * 128;
#pragma unroll
      for (int it = 0; it < 4; ++it) {
        rK[it] = *(const bf16x8*)(Kbase + (size_t)(k0n + 32 * it) * DK_);
        rV[it] = *(const bf16x8*)(Vbase + (size_t)(16 * it) * S_ + k0n);
      }
    }

    if (kt < myNkt) {
      const int k0 = kt * 128;
      f32x4 st[8];
#pragma unroll
      for (int j = 0; j < 8; ++j) {
        bf16x8 kf0 = *(const bf16x8*)&Kld[16 * j + l15][quad * 8];
        bf16x8 kf1 = *(const bf16x8*)&Kld[16 * j + l15][32 + quad * 8];
        st[j] = mfma_bf16(kf0, qf[0], fzero);
        st[j] = mfma_bf16(kf1, qf[1], st[j]);
      }

      if (kt == myNkt - 1) {
#pragma unroll
        for (int j = 0; j < 8; ++j)
#pragma unroll
          for (int r = 0; r < 4; ++r) {
            const int kcg = k0 + 16 * j + quad * 4 + r;
            if (kcg > qg) st[j][r] = -1.0e9f;
          }
      }

      float tm = st[0][0];
#pragma unroll
      for (int j = 0; j < 8; ++j)
#pragma unroll
        for (int r = 0; r < 4; ++r) tm = fmaxf(tm, st[j][r]);
      tm = fmaxf(tm, __shfl_xor(tm, 16));
      tm = fmaxf(tm, __shfl_xor(tm, 32));

      const float mnew = fmaxf(mI, tm);
      const float al = exp2_fast(mI - mnew);
      mI = mnew;
      float rs = 0.f;
#pragma unroll
      for (int j = 0; j < 8; ++j)
#pragma unroll
        for (int r = 0; r < 4; ++r) {
          const float pv = exp2_fast(st[j][r] - mnew);
          st[j][r] = pv;
          rs += pv;
        }
      rs += __shfl_xor(rs, 16);
      rs += __shfl_xor(rs, 32);
      lI = lI * al + rs;
#pragma unroll
      for (int jd = 0; jd < 4; ++jd)
#pragma unroll
        for (int r = 0; r < 4; ++r) accO[jd][r] *= al;

      bf16x4 pb[8];
#pragma unroll
      for (int j = 0; j < 8; ++j) {
        pb[j][0] = (__bf16)st[j][0]; pb[j][1] = (__bf16)st[j][1];
        pb[j][2] = (__bf16)st[j][2]; pb[j][3] = (__bf16)st[j][3];
      }

#pragma unroll
      for (int jd = 0; jd < 4; ++jd)
#pragma unroll
        for (int j = 0; j < 8; ++j) {
          bf16x4 vf = *(const bf16x4*)&Vld[16 * jd + l15][16 * j + quad * 4];
          accO[jd] = mfma16(vf, pb[j], accO[jd]);
        }
    }
    __syncthreads();
  }

  // ---- store UNNORMALIZED partials: Opart[half][bh][q][64] + (m,l) ----
  __hip_bfloat16* Obase = half ? Op1 : Op0;
#pragma unroll
  for (int jd = 0; jd < 4; ++jd) {
    bf16x4 ov;
#pragma unroll
    for (int r = 0; r < 4; ++r) ov[r] = (__bf16)accO[jd][r];
    *(bf16x4*)(Obase + ((size_t)bh * S_ + qg) * 64 + 16 * jd + quad * 4) = ov;
  }
  if (quad == 0) {
    float2 v; v.x = mI; v.y = lI;
    mlbuf[(size_t)(half * 24 + bh) * S_ + qg] = v;
  }
}

// ---------------------------------------------------------------------------
// Merge the two split-KV halves. In-place into Op0 ([bh][q][64] bf16).
// Grid 1536 x 256: one thread per 8 output elements.
// ---------------------------------------------------------------------------
__global__ __launch_bounds__(256)
void fa_merge(__hip_bfloat16* __restrict__ Op0,
              const __hip_bfloat16* __restrict__ Op1,
              const float2* __restrict__ ml)
{
  const int tid = blockIdx.x * 256 + threadIdx.x;   // 0..393215
  const int row = tid >> 3;                         // bh*2048 + q
  const int d8  = tid & 7;
  const float2 ml0 = ml[row];
  const float2 ml1 = ml[24 * S_ + row];
  const float m  = fmaxf(ml0.x, ml1.x);
  const float w0 = exp2_fast(ml0.x - m);
  const float w1 = exp2_fast(ml1.x - m);
  const float inv = 1.f / (ml0.y * w0 + ml1.y * w1);
  const float f0 = w0 * inv, f1 = w1 * inv;
  const size_t base = (size_t)row * 64 + d8 * 8;
  bf16x8 a = *(const bf16x8*)(Op0 + base);
  bf16x8 b = *(const bf16x8*)(Op1 + base);
  bf16x8 o;
#pragma unroll
  for (int i = 0; i < 8; ++i)
    o[i] = (__bf16)((float)a[i] * f0 + (float)b[i] * f1);
  *(bf16x8*)(Op0 + base) = o;
}

// ---------------------------------------------------------------------------
// Output projection v3: 64x64 tile, grid (64,12)=768 (3/CU). A is read from
// the merged attention buffer in [bh][q][64] layout (address remap in the
// staging gload16); B = Wo bf16. out(fp32) = A @ Wo^T + bo.
// ---------------------------------------------------------------------------
__global__ __launch_bounds__(256, 4)
void o_proj(const __hip_bfloat16* __restrict__ Xp,   // [bh][q][64] merged attn
            const __hip_bfloat16* __restrict__ Wob,
            const float* __restrict__ bias,
            float* __restrict__ outf)
{
  __shared__ alignas(16) __hip_bfloat16 Ald[64 * 32];
  __shared__ alignas(16) __hip_bfloat16 Bld[64 * 32];

  const int t    = threadIdx.x;
  const int w    = t >> 6;
  const int lane = t & 63;
  const int l15  = lane & 15;
  const int quad = lane >> 4;
  const int m0 = blockIdx.x * 64;
  const int n0 = blockIdx.y * 64;
  const int wm = (w >> 1) * 32;
  const int wn = (w & 1) * 32;

  const f32x4 fzero = {0.f, 0.f, 0.f, 0.f};
  f32x4 acc[2][2];
#pragma unroll
  for (int i = 0; i < 2; ++i)
#pragma unroll
    for (int j = 0; j < 2; ++j) acc[i][j] = fzero;

  // A staging: row m0+(t>>2); source col granule cg = k0/8 + sw, where
  // sw is the L-layout swizzle. In [bh][q][64]: h = cg>>3, dg = cg&7.
  const int arow = t >> 2;
  const int asw  = (t & 3) ^ ((arow >> 1) & 3);
  const int m_g  = m0 + arow;
  const int ab   = m_g >> 11, as = m_g & (S_ - 1);
  const size_t arowbase = ((size_t)ab * H_) * S_ * 64 + (size_t)as * 64;

  const int bsw = asw;   // same formula
  const __hip_bfloat16* Bs = Wob + (size_t)(n0 + arow) * D_ + bsw * 8;
  __hip_bfloat16* Ad = &Ald[t * 8];
  __hip_bfloat16* Bd = &Bld[t * 8];

  int agrn[2], bgrn[2];
#pragma unroll
  for (int i = 0; i < 2; ++i) {
    int row = wm + 16 * i + l15;
    agrn[i] = (row * 4 + (quad ^ ((row >> 1) & 3))) * 8;
    row = wn + 16 * i + l15;
    bgrn[i] = (row * 4 + (quad ^ ((row >> 1) & 3))) * 8;
  }

  for (int k0 = 0; k0 < D_; k0 += 32) {
    const int cg = (k0 >> 3) + asw;
    const __hip_bfloat16* Ap =
        Xp + arowbase + (size_t)(cg >> 3) * (S_ * 64) + (cg & 7) * 8;
    gload16(Ap, Ad);
    gload16(Bs + k0, Bd);
    __syncthreads();

    bf16x8 af[2], bfr[2];
#pragma unroll
    for (int i = 0; i < 2; ++i) af[i]  = *(const bf16x8*)&Ald[agrn[i]];
#pragma unroll
    for (int j = 0; j < 2; ++j) bfr[j] = *(const bf16x8*)&Bld[bgrn[j]];
#pragma unroll
    for (int i = 0; i < 2; ++i)
#pragma unroll
      for (int j = 0; j < 2; ++j)
        acc[i][j] = mfma_bf16(af[i], bfr[j], acc[i][j]);
    __syncthreads();
  }

#pragma unroll
  for (int j = 0; j < 2; ++j) {
    const int n_g = n0 + wn + 16 * j + l15;
    const float bv = bias[n_g];
#pragma unroll
    for (int i = 0; i < 2; ++i) {
      const int mbase = m0 + wm + 16 * i + quad * 4;
#pragma unroll
      for (int r = 0; r < 4; ++r)
        outf[(size_t)(mbase + r) * D_ + n_g] = acc[i][j][r] + bv;
    }
  }
}

// ---------------------------------------------------------------------------
extern "C" void kernel_launch(void* const* d_in, const int* in_sizes, int n_in,
                              void* d_out, int out_size, void* d_ws, size_t ws_size,
                              hipStream_t stream) {
  (void)in_sizes; (void)n_in; (void)out_size; (void)ws_size;
  const float* Q  = (const float*)d_in[0];
  const float* K  = (const float*)d_in[1];
  const float* V  = (const float*)d_in[2];
  // d_in[3] = causal mask (tril by construction) -- hardcoded in flash_attn
  const float* Wq = (const float*)d_in[4];
  const float* bq = (const float*)d_in[5];
  const float* Wk = (const float*)d_in[6];
  const float* bk = (const float*)d_in[7];
  const float* Wv = (const float*)d_in[8];
  const float* bv = (const float*)d_in[9];
  const float* Wo = (const float*)d_in[10];
  const float* bo = (const float*)d_in[11];
  float* out = (float*)d_out;

  const size_t WEL = (size_t)4 * 589824;   // 4 bf16 weight matrices
  const size_t NEL = (size_t)2 * S_ * D_;  // 3,145,728 el per activation
  __hip_bfloat16* wb    = (__hip_bfloat16*)d_ws;
  __hip_bfloat16* q_ws  = wb + WEL;
  __hip_bfloat16* k_ws  = q_ws  + NEL;
  __hip_bfloat16* vT_ws = k_ws  + NEL;
  __hip_bfloat16* op0   = vT_ws + NEL;     // [24][2048][64] bf16 (merged here)
  __hip_bfloat16* op1   = op0   + NEL;
  float2*         mlbuf = (float2*)(op1 + NEL);  // [2][24][2048] float2

  conv_w<<<1152, 256, 0, stream>>>(Wq, Wk, Wv, Wo, wb);
  qkv_proj<<<dim3(32, 6, 3), 256, 0, stream>>>(Q, K, V, wb, bq, bk, bv,
                                               q_ws, k_ws, vT_ws);
  flash_attn<<<1536, 256, 0, stream>>>(q_ws, k_ws, vT_ws, op0, op1, mlbuf);
  fa_merge<<<1536, 256, 0, stream>>>(op0, op1, mlbuf);
  o_proj<<<dim3(64, 12), 256, 0, stream>>>(op0, wb + (size_t)3 * 589824, bo, out);
}